// Round 6
// baseline (21777.927 us; speedup 1.0000x reference)
//
#include <hip/hip_runtime.h>

// ACT (adaptive computation time) RNN, T=8192, IO=32, H=256, M=4, EPS=0.01.
// ALL float32 in and out. Rounds 4/5 killed the container: ws footprint was
// 16.84 MB (> likely 16 MiB ws_size) -> OOB global stores -> GPU fault.
// Fix: AccS aliases U in-place (U[t] is dead after step t), ws = 8.45 MB.
// act_chain: 1 block, 1024 threads; thread (w,rg,c) owns rows w*16+rg*4..+3 x
// K-chunk [c*16,c*16+16) of Ws in 64 VGPRs; s in LDS (stride-20 swizzle);
// 16-lane DPP row_ror butterfly reduces the dot; halting dot via per-wave
// lane63 -> plds[2][16] ping-pong (race-free), summed by all threads.

#define T_  8192
#define IO_ 32
#define H_  256

// x + dpp_perm(x); invalid lanes add x+x (only lane63 consumed after bcasts).
template<int CTRL>
__device__ __forceinline__ float dpp_addf(float x) {
    int xi = __builtin_bit_cast(int, x);
    int d = __builtin_amdgcn_update_dpp(xi, xi, CTRL, 0xF, 0xF, false);
    return x + __builtin_bit_cast(float, d);
}

// ---------------- k_prep: WxpT[io][h] = (Wx[:,:H]@Wp)^T, c = Wx[:,:H]@bp + b
__global__ void k_prep(const float* __restrict__ Wx,
                       const float* __restrict__ Wp,
                       const float* __restrict__ bp,
                       const float* __restrict__ b,
                       float* __restrict__ WxpT, float* __restrict__ cvec) {
    int h = blockIdx.x;           // 0..255
    int t = threadIdx.x;          // 0..63
    __shared__ float wxrow[H_];
    for (int j = t; j < H_; j += 64) wxrow[j] = Wx[h * (H_ + 1) + j];
    __syncthreads();
    if (t < IO_) {
        float acc = 0.0f;
        for (int j = 0; j < H_; ++j) acc += wxrow[j] * Wp[j * IO_ + t];
        WxpT[t * H_ + h] = acc;
    } else if (t == IO_) {
        float acc = b[h];
        for (int j = 0; j < H_; ++j) acc += wxrow[j] * bp[j];
        cvec[h] = acc;
    }
}

// ---------------- k_u: U[t][h] = WxpT^T x_t + c  (f32) ----------------
__global__ void k_u(const float* __restrict__ x,
                    const float* __restrict__ WxpT,
                    const float* __restrict__ cvec,
                    float* __restrict__ U) {
    int t0 = blockIdx.x * 8;
    int tid = threadIdx.x;        // 256
    __shared__ float xsf[8 * IO_];
    xsf[tid] = x[(size_t)t0 * IO_ + tid];
    __syncthreads();
    int h = tid;
    float base = cvec[h];
    for (int tt = 0; tt < 8; ++tt) {
        float acc = base;
        #pragma unroll
        for (int io = 0; io < IO_; ++io)
            acc += WxpT[io * H_ + h] * xsf[tt * IO_ + io];
        U[(size_t)(t0 + tt) * H_ + h] = acc;
    }
}

// ---------------- act_chain: sequential scan, all-f32 ----------------
// UAcc: on entry U[t][h]; on exit AccS[t][h] (in-place alias, row t dead
// after step t — next step's u is register-prefetched before the write).
__global__ __launch_bounds__(1024) void act_chain(
    const float* __restrict__ Ws,
    const float* __restrict__ Wx,
    const float* __restrict__ wh,
    const float* __restrict__ bh1,
    const float* __restrict__ h0,
    float* __restrict__ UAcc,
    float* __restrict__ cumArr,
    float* __restrict__ pc_out)
{
    // s storage swizzled: chunk c's 16 floats at [c*20 .. c*20+16).
    __shared__ __align__(16) float sbuf[2][320];
    __shared__ float plds[2][16];

    const int tid = threadIdx.x;
    const int w   = tid >> 6;        // wave 0..15
    const int l   = tid & 63;
    const int rg  = l >> 4;          // row-group within wave (0..3)
    const int c   = l & 15;          // K-chunk (16 floats)
    const int rowbase = w * 16 + rg * 4;

    // Ws tile: 4 rows x 16 cols, f32, 64 VGPRs
    float4 wq[4][4];
    #pragma unroll
    for (int r = 0; r < 4; ++r) {
        const float4* src = (const float4*)(Ws + (size_t)(rowbase + r) * H_ + c * 16);
        wq[r][0] = src[0]; wq[r][1] = src[1]; wq[r][2] = src[2]; wq[r][3] = src[3];
    }

    float wl4[4], whv4[4];
    #pragma unroll
    for (int r = 0; r < 4; ++r) {
        wl4[r]  = Wx[(size_t)(rowbase + r) * (H_ + 1) + H_];  // first-step flag col
        whv4[r] = wh[rowbase + r];
    }
    const float bhf = bh1[0];
    const float thresh = 1.0f - 0.01f;

    if (tid < H_) sbuf[0][(tid >> 4) * 20 + (tid & 15)] = h0[tid];
    __syncthreads();

    int cur = 0, pp = 0;
    float pc = 0.0f;

    float u4a[4];
    {
        float4 uv = *(const float4*)(UAcc + rowbase);
        u4a[0] = uv.x; u4a[1] = uv.y; u4a[2] = uv.z; u4a[3] = uv.w;
    }

    for (int t = 0; t < T_; ++t) {
        int tn = (t + 1 < T_) ? t + 1 : t;
        float4 un = *(const float4*)(UAcc + (size_t)tn * H_ + rowbase);  // prefetch

        float accs[4] = {0.f, 0.f, 0.f, 0.f};
        float cum = 0.0f, nup = 0.0f, remt = 0.0f;
        float sn[4];

        #pragma unroll 1
        for (int n = 0; n < 4; ++n) {
            const float4* sp = (const float4*)(&sbuf[cur][c * 20]);
            float4 s0 = sp[0], s1 = sp[1], s2 = sp[2], s3 = sp[3];

            float y[4];
            #pragma unroll
            for (int r = 0; r < 4; ++r) {
                float a;
                a  = wq[r][0].x * s0.x + wq[r][0].y * s0.y + wq[r][0].z * s0.z + wq[r][0].w * s0.w;
                a += wq[r][1].x * s1.x + wq[r][1].y * s1.y + wq[r][1].z * s1.z + wq[r][1].w * s1.w;
                a += wq[r][2].x * s2.x + wq[r][2].y * s2.y + wq[r][2].z * s2.z + wq[r][2].w * s2.w;
                a += wq[r][3].x * s3.x + wq[r][3].y * s3.y + wq[r][3].z * s3.z + wq[r][3].w * s3.w;
                a = dpp_addf<0x121>(a);   // row_ror:1
                a = dpp_addf<0x122>(a);   // row_ror:2
                a = dpp_addf<0x124>(a);   // row_ror:4
                a = dpp_addf<0x128>(a);   // row_ror:8
                y[r] = a;
            }

            float part = 0.0f;
            #pragma unroll
            for (int r = 0; r < 4; ++r) {
                float yy = y[r] + u4a[r] + ((n == 0) ? wl4[r] : 0.0f);
                float e = __expf(2.0f * yy);                       // tanh
                sn[r] = 1.0f - 2.0f * __builtin_amdgcn_rcpf(e + 1.0f);
                part += whv4[r] * sn[r];
            }

            int nxt = cur ^ 1;
            if (c == 0)
                *(float4*)(&sbuf[nxt][w * 20 + rg * 4]) =
                    make_float4(sn[0], sn[1], sn[2], sn[3]);

            // wave sum of part (row-uniform): bcast15 then bcast31 -> lane63
            float x1 = dpp_addf<0x142>(part);  // row_bcast15
            float x2 = dpp_addf<0x143>(x1);    // row_bcast31
            if (l == 63) plds[pp][w] = x2;
            __syncthreads();

            float dot = 0.0f;
            #pragma unroll
            for (int i = 0; i < 16; ++i) dot += plds[pp][i];
            pp ^= 1;
            float p = __builtin_amdgcn_rcpf(1.0f + __expf(-(dot + bhf)));
            bool halt = (cum + p > thresh) || (n == 3);
            float hw = 1.0f - cum;
            float wn = halt ? hw : p;
            #pragma unroll
            for (int r = 0; r < 4; ++r) accs[r] += wn * sn[r];
            nup += 1.0f;
            cum += wn;
            if (halt) { remt = hw; break; }   // exact: w==0 for all later n
            cur = nxt;
        }

        pc = (pc + nup + remt) * (1.0f / (float)T_);

        int hb = cur ^ 1;   // dead buffer -> becomes h
        if (c == 0) {
            float4 hv = make_float4(accs[0], accs[1], accs[2], accs[3]);
            *(float4*)(&sbuf[hb][w * 20 + rg * 4]) = hv;
            *(float4*)(UAcc + (size_t)t * H_ + rowbase) = hv;   // AccS in-place
        }
        if (tid == 0) cumArr[t] = cum;
        cur = hb;
        u4a[0] = un.x; u4a[1] = un.y; u4a[2] = un.z; u4a[3] = un.w;
        __syncthreads();
    }
    if (tid == 0) pc_out[0] = pc;
}

// ---------------- k_out: ys[t] = Wo@acc_s[t] + cum[t]*bo ----------------
__global__ void k_out(const float* __restrict__ AccS,
                      const float* __restrict__ Wo,
                      const float* __restrict__ bo,
                      const float* __restrict__ cumArr,
                      float* __restrict__ ys) {
    int t0 = blockIdx.x * 8;
    int tid = threadIdx.x;   // 256
    __shared__ float wo[IO_ * 257];
    __shared__ float as[8 * 260];
    for (int i = tid; i < IO_ * H_; i += 256) {
        int o = i / H_, h = i % H_;
        wo[o * 257 + h] = Wo[i];
    }
    for (int i = tid; i < 8 * H_; i += 256) {
        int tt = i / H_, h = i % H_;
        as[tt * 260 + h] = AccS[(size_t)t0 * H_ + i];
    }
    __syncthreads();
    int tt = tid >> 5, o = tid & 31;
    float acc = cumArr[t0 + tt] * bo[o];
    #pragma unroll 4
    for (int h = 0; h < H_; ++h) acc += wo[o * 257 + h] * as[tt * 260 + h];
    ys[(size_t)(t0 + tt) * IO_ + o] = acc;
}

extern "C" void kernel_launch(void* const* d_in, const int* in_sizes, int n_in,
                              void* d_out, int out_size, void* d_ws, size_t ws_size,
                              hipStream_t stream) {
    const float* x  = (const float*)d_in[0];
    const float* h0 = (const float*)d_in[1];
    const float* Wp = (const float*)d_in[2];
    const float* bp = (const float*)d_in[3];
    const float* Wx = (const float*)d_in[4];
    const float* Ws = (const float*)d_in[5];
    const float* b  = (const float*)d_in[6];
    const float* wh = (const float*)d_in[7];
    const float* bh = (const float*)d_in[8];
    const float* Wo = (const float*)d_in[9];
    const float* bo = (const float*)d_in[10];
    float* out = (float*)d_out;   // f32 output: ys[8192*32] then pc

    char* ws = (char*)d_ws;
    float* WxpT = (float*)ws;                                    //  32 KB
    float* cvec = (float*)(ws + 32768);                          //   1 KB
    float* cumA = (float*)(ws + 33792);                          //  32 KB
    float* UAcc = (float*)(ws + 66560);                          //   8 MB f32
    // total ws use: 66560 + 8 MB = 8.45 MB (AccS aliases UAcc in-place)

    k_prep<<<H_, 64, 0, stream>>>(Wx, Wp, bp, b, WxpT, cvec);
    k_u<<<T_ / 8, 256, 0, stream>>>(x, WxpT, cvec, UAcc);
    act_chain<<<1, 1024, 0, stream>>>(Ws, Wx, wh, bh, h0, UAcc, cumA,
                                      out + (size_t)T_ * IO_);
    k_out<<<T_ / 8, 256, 0, stream>>>(UAcc, Wo, bo, cumA, out);
}

// Round 7
// 14745.398 us; speedup vs baseline: 1.4769x; 1.4769x over previous
//
#include <hip/hip_runtime.h>

// ACT RNN, T=8192, IO=32, H=256, M=4, EPS=0.01. All f32 in/out.
// Round 7: act_chain reshaped 1024->512 threads (8 waves, 2/SIMD -> 256-VGPR
// budget) so the Ws tile (4 rows x 32 cols = 128 VGPR/thread) is truly
// register-resident (round 6 showed VGPR_Count=60 => tile was AGPR-parked or
// re-loaded per iter). Reduce over 8 chunk-lanes with full-rate DPP
// (quad_perm xor1/xor2 + row_half_mirror). U-loads / AccS+cum-stores batched
// per 4 timesteps to amortize the vmcnt(0) drain at each barrier.
// ws footprint stays 8.45 MB (AccS aliases U in place; ws_size is 16 MiB).

#define T_  8192
#define IO_ 32
#define H_  256

template<int CTRL>
__device__ __forceinline__ float dpp_addf(float x) {
    int xi = __builtin_bit_cast(int, x);
    int d = __builtin_amdgcn_update_dpp(xi, xi, CTRL, 0xF, 0xF, false);
    return x + __builtin_bit_cast(float, d);
}

// ---------------- k_prep: WxpT[io][h] = (Wx[:,:H]@Wp)^T, c = Wx[:,:H]@bp + b
__global__ void k_prep(const float* __restrict__ Wx,
                       const float* __restrict__ Wp,
                       const float* __restrict__ bp,
                       const float* __restrict__ b,
                       float* __restrict__ WxpT, float* __restrict__ cvec) {
    int h = blockIdx.x;           // 0..255
    int t = threadIdx.x;          // 0..63
    __shared__ float wxrow[H_];
    for (int j = t; j < H_; j += 64) wxrow[j] = Wx[h * (H_ + 1) + j];
    __syncthreads();
    if (t < IO_) {
        float acc = 0.0f;
        for (int j = 0; j < H_; ++j) acc += wxrow[j] * Wp[j * IO_ + t];
        WxpT[t * H_ + h] = acc;
    } else if (t == IO_) {
        float acc = b[h];
        for (int j = 0; j < H_; ++j) acc += wxrow[j] * bp[j];
        cvec[h] = acc;
    }
}

// ---------------- k_u: U[t][h] = WxpT^T x_t + c  (f32) ----------------
__global__ void k_u(const float* __restrict__ x,
                    const float* __restrict__ WxpT,
                    const float* __restrict__ cvec,
                    float* __restrict__ U) {
    int t0 = blockIdx.x * 8;
    int tid = threadIdx.x;        // 256
    __shared__ float xsf[8 * IO_];
    xsf[tid] = x[(size_t)t0 * IO_ + tid];
    __syncthreads();
    int h = tid;
    float base = cvec[h];
    for (int tt = 0; tt < 8; ++tt) {
        float acc = base;
        #pragma unroll
        for (int io = 0; io < IO_; ++io)
            acc += WxpT[io * H_ + h] * xsf[tt * IO_ + io];
        U[(size_t)(t0 + tt) * H_ + h] = acc;
    }
}

// ---------------- act_chain ----------------
// Thread (w, rg, c): rows rowbase..rowbase+3 (rowbase = w*32+rg*4) x cols
// [c*32, c*32+32) of Ws in 128 VGPRs. s in LDS, chunk c at float offset c*36
// (stride-36: reads conflict-free). UAcc: in U[t][h], out AccS[t][h] in place.
__global__ __launch_bounds__(512, 2) void act_chain(
    const float* __restrict__ Ws,
    const float* __restrict__ Wx,
    const float* __restrict__ wh,
    const float* __restrict__ bh1,
    const float* __restrict__ h0,
    float* __restrict__ UAcc,
    float* __restrict__ cumArr,
    float* __restrict__ pc_out)
{
    __shared__ __align__(16) float sbuf[2][288];   // 8 chunks * 36
    __shared__ __align__(16) float plds[2][8];

    const int tid = threadIdx.x;
    const int w   = tid >> 6;        // wave 0..7
    const int l   = tid & 63;
    const int rg  = l >> 3;          // row-group 0..7
    const int c   = l & 7;           // 32-col chunk 0..7
    const int rowbase = w * 32 + rg * 4;

    // Ws tile: 4 rows x 32 cols, 128 VGPRs
    float4 wq[4][8];
    #pragma unroll
    for (int r = 0; r < 4; ++r) {
        const float4* src = (const float4*)(Ws + (size_t)(rowbase + r) * H_ + c * 32);
        #pragma unroll
        for (int k = 0; k < 8; ++k) wq[r][k] = src[k];
    }

    float wl4[4], whv4[4];
    #pragma unroll
    for (int r = 0; r < 4; ++r) {
        wl4[r]  = Wx[(size_t)(rowbase + r) * (H_ + 1) + H_];  // first-step flag col
        whv4[r] = wh[rowbase + r];
    }
    const float bhf = bh1[0];
    const float thresh = 1.0f - 0.01f;

    if (tid < H_) sbuf[0][(tid >> 5) * 36 + (tid & 31)] = h0[tid];
    __syncthreads();

    int cur = 0, pp = 0;
    float pc = 0.0f;

    #pragma unroll 1
    for (int tg = 0; tg < T_ / 4; ++tg) {
        // batched u-loads for 4 timesteps (amortizes barrier vmcnt drains)
        float4 un[4];
        #pragma unroll
        for (int k = 0; k < 4; ++k)
            un[k] = *(const float4*)(UAcc + (size_t)(tg * 4 + k) * H_ + rowbase);

        float4 av[4];      // acc_s for the 4 steps
        float  cu4[4];     // cum for the 4 steps

        #pragma unroll
        for (int k = 0; k < 4; ++k) {
            const float u0 = un[k].x, u1 = un[k].y, u2 = un[k].z, u3 = un[k].w;

            float accs[4] = {0.f, 0.f, 0.f, 0.f};
            float cum = 0.0f, nup = 0.0f, remt = 0.0f;
            float sn[4];

            #pragma unroll 1
            for (int n = 0; n < 4; ++n) {
                const float4* sp = (const float4*)(&sbuf[cur][c * 36]);
                float4 sv[8];
                #pragma unroll
                for (int q = 0; q < 8; ++q) sv[q] = sp[q];

                float y[4];
                #pragma unroll
                for (int r = 0; r < 4; ++r) {
                    float a = 0.0f;
                    #pragma unroll
                    for (int q = 0; q < 8; ++q) {
                        a += wq[r][q].x * sv[q].x;
                        a += wq[r][q].y * sv[q].y;
                        a += wq[r][q].z * sv[q].z;
                        a += wq[r][q].w * sv[q].w;
                    }
                    // reduce over the 8 chunk-lanes: xor1, xor2, cross-quad
                    a = dpp_addf<0xB1>(a);    // quad_perm [1,0,3,2]
                    a = dpp_addf<0x4E>(a);    // quad_perm [2,3,0,1]
                    a = dpp_addf<0x141>(a);   // row_half_mirror
                    y[r] = a;
                }

                float part = 0.0f;
                float uu[4] = {u0, u1, u2, u3};
                #pragma unroll
                for (int r = 0; r < 4; ++r) {
                    float yy = y[r] + uu[r] + ((n == 0) ? wl4[r] : 0.0f);
                    float e = __expf(2.0f * yy);                     // tanh
                    sn[r] = 1.0f - 2.0f * __builtin_amdgcn_rcpf(e + 1.0f);
                    part += whv4[r] * sn[r];
                }

                int nxt = cur ^ 1;
                if (c == 0)
                    *(float4*)(&sbuf[nxt][w * 36 + rg * 4]) =
                        make_float4(sn[0], sn[1], sn[2], sn[3]);

                // wave sum of part: xor8 then bcast up to lane63
                part = dpp_addf<0x128>(part);   // row_ror:8 == xor8 here
                part = dpp_addf<0x142>(part);   // row_bcast15
                part = dpp_addf<0x143>(part);   // row_bcast31 -> lane63 total
                if (l == 63) plds[pp][w] = part;
                __syncthreads();

                float4 pa = *(const float4*)(&plds[pp][0]);
                float4 pb = *(const float4*)(&plds[pp][4]);
                float dot = ((pa.x + pa.y) + (pa.z + pa.w)) +
                            ((pb.x + pb.y) + (pb.z + pb.w));
                pp ^= 1;
                float p = __builtin_amdgcn_rcpf(1.0f + __expf(-(dot + bhf)));
                bool halt = (cum + p > thresh) || (n == 3);
                float hw = 1.0f - cum;
                float wn = halt ? hw : p;
                #pragma unroll
                for (int r = 0; r < 4; ++r) accs[r] += wn * sn[r];
                nup += 1.0f;
                cum += wn;
                if (halt) { remt = hw; break; }   // exact: w==0 afterwards
                cur = nxt;
            }

            pc = (pc + nup + remt) * (1.0f / (float)T_);

            int hb = cur ^ 1;   // dead buffer -> becomes h
            av[k] = make_float4(accs[0], accs[1], accs[2], accs[3]);
            cu4[k] = cum;
            if (c == 0)
                *(float4*)(&sbuf[hb][w * 36 + rg * 4]) = av[k];
            cur = hb;
            __syncthreads();
        }

        // batched stores: acc_s (in place over U rows, now dead) + cum
        if (c == 0) {
            #pragma unroll
            for (int k = 0; k < 4; ++k)
                *(float4*)(UAcc + (size_t)(tg * 4 + k) * H_ + rowbase) = av[k];
        }
        if (tid == 0) {
            #pragma unroll
            for (int k = 0; k < 4; ++k) cumArr[tg * 4 + k] = cu4[k];
        }
    }
    if (tid == 0) pc_out[0] = pc;
}

// ---------------- k_out: ys[t] = Wo@acc_s[t] + cum[t]*bo ----------------
__global__ void k_out(const float* __restrict__ AccS,
                      const float* __restrict__ Wo,
                      const float* __restrict__ bo,
                      const float* __restrict__ cumArr,
                      float* __restrict__ ys) {
    int t0 = blockIdx.x * 8;
    int tid = threadIdx.x;   // 256
    __shared__ float wo[IO_ * 257];
    __shared__ float as[8 * 260];
    for (int i = tid; i < IO_ * H_; i += 256) {
        int o = i / H_, h = i % H_;
        wo[o * 257 + h] = Wo[i];
    }
    for (int i = tid; i < 8 * H_; i += 256) {
        int tt = i / H_, h = i % H_;
        as[tt * 260 + h] = AccS[(size_t)t0 * H_ + i];
    }
    __syncthreads();
    int tt = tid >> 5, o = tid & 31;
    float acc = cumArr[t0 + tt] * bo[o];
    #pragma unroll 4
    for (int h = 0; h < H_; ++h) acc += wo[o * 257 + h] * as[tt * 260 + h];
    ys[(size_t)(t0 + tt) * IO_ + o] = acc;
}

extern "C" void kernel_launch(void* const* d_in, const int* in_sizes, int n_in,
                              void* d_out, int out_size, void* d_ws, size_t ws_size,
                              hipStream_t stream) {
    const float* x  = (const float*)d_in[0];
    const float* h0 = (const float*)d_in[1];
    const float* Wp = (const float*)d_in[2];
    const float* bp = (const float*)d_in[3];
    const float* Wx = (const float*)d_in[4];
    const float* Ws = (const float*)d_in[5];
    const float* b  = (const float*)d_in[6];
    const float* wh = (const float*)d_in[7];
    const float* bh = (const float*)d_in[8];
    const float* Wo = (const float*)d_in[9];
    const float* bo = (const float*)d_in[10];
    float* out = (float*)d_out;   // f32: ys[8192*32] then pc

    char* ws = (char*)d_ws;
    float* WxpT = (float*)ws;                                    //  32 KB
    float* cvec = (float*)(ws + 32768);                          //   1 KB
    float* cumA = (float*)(ws + 33792);                          //  32 KB
    float* UAcc = (float*)(ws + 66560);                          //   8 MB f32
    // total ws use: 8.45 MB (AccS aliases UAcc in place)

    k_prep<<<H_, 64, 0, stream>>>(Wx, Wp, bp, b, WxpT, cvec);
    k_u<<<T_ / 8, 256, 0, stream>>>(x, WxpT, cvec, UAcc);
    act_chain<<<1, 512, 0, stream>>>(Ws, Wx, wh, bh, h0, UAcc, cumA,
                                     out + (size_t)T_ * IO_);
    k_out<<<T_ / 8, 256, 0, stream>>>(UAcc, Wo, bo, cumA, out);
}

// Round 8
// 12102.477 us; speedup vs baseline: 1.7995x; 1.2184x over previous
//
#include <hip/hip_runtime.h>

// ACT RNN, T=8192, IO=32, H=256, M=4, EPS=0.01. All f32 in/out.
// Round 8: instruction diet for the VALU-issue-bound act_chain (round 7:
// ~91% of one CU busy issuing VALU, ~475 wave-instrs/ponder-iter).
//  - float2 ext-vectors -> v_pk_fma_f32: 64 pk_fma vs 128 fma per thread-iter
//  - R=2 rows/thread x 64 cols (c=lane&3): y-butterfly 4->2 DPP/row-set,
//    tanh 4->2/thread; part-sum = ror4+ror8+bcast15+bcast31 (4 DPP)
//  - exp2-form tanh/sigmoid, flag pre-added into u for n==0
//  - group-of-4 timestep VMEM batching (amortize barrier vmcnt(0) drains)
// ws = 8.45 MB (AccS aliases U in place; ws_size 16 MiB).

#define T_  8192
#define IO_ 32
#define H_  256

typedef __attribute__((ext_vector_type(2))) float v2f;

template<int CTRL>
__device__ __forceinline__ float dpp_addf(float x) {
    int xi = __builtin_bit_cast(int, x);
    int d = __builtin_amdgcn_update_dpp(xi, xi, CTRL, 0xF, 0xF, false);
    return x + __builtin_bit_cast(float, d);
}

// ---------------- k_prep: WxpT[io][h] = (Wx[:,:H]@Wp)^T, c = Wx[:,:H]@bp + b
__global__ void k_prep(const float* __restrict__ Wx,
                       const float* __restrict__ Wp,
                       const float* __restrict__ bp,
                       const float* __restrict__ b,
                       float* __restrict__ WxpT, float* __restrict__ cvec) {
    int h = blockIdx.x;           // 0..255
    int t = threadIdx.x;          // 0..63
    __shared__ float wxrow[H_];
    for (int j = t; j < H_; j += 64) wxrow[j] = Wx[h * (H_ + 1) + j];
    __syncthreads();
    if (t < IO_) {
        float acc = 0.0f;
        for (int j = 0; j < H_; ++j) acc += wxrow[j] * Wp[j * IO_ + t];
        WxpT[t * H_ + h] = acc;
    } else if (t == IO_) {
        float acc = b[h];
        for (int j = 0; j < H_; ++j) acc += wxrow[j] * bp[j];
        cvec[h] = acc;
    }
}

// ---------------- k_u: U[t][h] = WxpT^T x_t + c  (f32) ----------------
__global__ void k_u(const float* __restrict__ x,
                    const float* __restrict__ WxpT,
                    const float* __restrict__ cvec,
                    float* __restrict__ U) {
    int t0 = blockIdx.x * 8;
    int tid = threadIdx.x;        // 256
    __shared__ float xsf[8 * IO_];
    xsf[tid] = x[(size_t)t0 * IO_ + tid];
    __syncthreads();
    int h = tid;
    float base = cvec[h];
    for (int tt = 0; tt < 8; ++tt) {
        float acc = base;
        #pragma unroll
        for (int io = 0; io < IO_; ++io)
            acc += WxpT[io * H_ + h] * xsf[tt * IO_ + io];
        U[(size_t)(t0 + tt) * H_ + h] = acc;
    }
}

// ---------------- act_chain ----------------
// 512 threads / 8 waves. Lane (w, rg=l>>2, c=l&3): rows rowbase, rowbase+1
// (rowbase = w*32 + rg*2) x s-cols [c*64, c*64+64) of Ws as 64 v2f (128 VGPR).
// s in LDS, chunk c at float offset c*68 (conflict-free). UAcc in/out in place.
__global__ __launch_bounds__(512, 2) void act_chain(
    const float* __restrict__ Ws,
    const float* __restrict__ Wx,
    const float* __restrict__ wh,
    const float* __restrict__ bh1,
    const float* __restrict__ h0,
    float* __restrict__ UAcc,
    float* __restrict__ cumArr,
    float* __restrict__ pc_out)
{
    __shared__ __align__(16) float sbuf[2][4 * 68];
    __shared__ __align__(16) float plds[2][8];

    const int tid = threadIdx.x;
    const int w   = tid >> 6;        // wave 0..7
    const int l   = tid & 63;
    const int rg  = l >> 2;          // row-group 0..15 (2 rows each)
    const int c   = l & 3;           // 64-col chunk 0..3
    const int rowbase = w * 32 + rg * 2;
    const int schunk  = rowbase >> 6;         // h-write chunk
    const int soff    = rowbase & 63;

    // Ws tile: 2 rows x 64 cols as v2f[2][32] = 128 VGPRs
    v2f wt[2][32];
    #pragma unroll
    for (int r = 0; r < 2; ++r) {
        const float4* src = (const float4*)(Ws + (size_t)(rowbase + r) * H_ + c * 64);
        #pragma unroll
        for (int q = 0; q < 16; ++q) {
            float4 f = src[q];
            wt[r][2 * q]     = (v2f){f.x, f.y};
            wt[r][2 * q + 1] = (v2f){f.z, f.w};
        }
    }

    v2f wl2, whv2;
    wl2.x  = Wx[(size_t)rowbase * (H_ + 1) + H_];
    wl2.y  = Wx[(size_t)(rowbase + 1) * (H_ + 1) + H_];
    whv2.x = wh[rowbase];
    whv2.y = wh[rowbase + 1];
    const float bhf = bh1[0];
    const float thresh = 1.0f - 0.01f;
    const float L2E  = 1.4426950408889634f;   // log2(e)
    const float L2E2 = 2.8853900817779268f;   // 2*log2(e)

    if (tid < H_) sbuf[0][(tid >> 6) * 68 + (tid & 63)] = h0[tid];
    __syncthreads();

    int cur = 0, pp = 0;
    float pc = 0.0f;

    #pragma unroll 1
    for (int tg = 0; tg < T_ / 4; ++tg) {
        v2f un[4];
        #pragma unroll
        for (int k = 0; k < 4; ++k)
            un[k] = *(const v2f*)(UAcc + (size_t)(tg * 4 + k) * H_ + rowbase);

        v2f   av[4];
        float cu4[4];

        #pragma unroll
        for (int k = 0; k < 4; ++k) {
            const v2f uu1 = un[k];
            const v2f uu0 = uu1 + wl2;      // n==0: first-step flag folded in

            v2f accs = {0.f, 0.f};
            float cum = 0.0f, nup = 0.0f, remt = 0.0f;
            float sn0, sn1;

            #pragma unroll 1
            for (int n = 0; n < 4; ++n) {
                // dot: 2 rows x 64 cols, v_pk_fma_f32
                v2f acc0 = {0.f, 0.f}, acc1 = {0.f, 0.f};
                const float4* sp = (const float4*)(&sbuf[cur][c * 68]);
                #pragma unroll
                for (int q = 0; q < 16; ++q) {
                    float4 f = sp[q];
                    v2f sa = (v2f){f.x, f.y};
                    v2f sb = (v2f){f.z, f.w};
                    acc0 = acc0 + wt[0][2 * q] * sa;
                    acc0 = acc0 + wt[0][2 * q + 1] * sb;
                    acc1 = acc1 + wt[1][2 * q] * sa;
                    acc1 = acc1 + wt[1][2 * q + 1] * sb;
                }
                float y0 = acc0.x + acc0.y;
                float y1 = acc1.x + acc1.y;
                // reduce over the 4 c-lanes (quad): xor1, xor2
                y0 = dpp_addf<0xB1>(y0); y0 = dpp_addf<0x4E>(y0);
                y1 = dpp_addf<0xB1>(y1); y1 = dpp_addf<0x4E>(y1);

                v2f uu = (n == 0) ? uu0 : uu1;
                float yy0 = y0 + uu.x;
                float yy1 = y1 + uu.y;
                float e0 = __builtin_amdgcn_exp2f(yy0 * L2E2);
                float e1 = __builtin_amdgcn_exp2f(yy1 * L2E2);
                sn0 = __builtin_fmaf(-2.0f, __builtin_amdgcn_rcpf(e0 + 1.0f), 1.0f);
                sn1 = __builtin_fmaf(-2.0f, __builtin_amdgcn_rcpf(e1 + 1.0f), 1.0f);

                int nxt = cur ^ 1;
                if (c == 0)
                    *(v2f*)(&sbuf[nxt][schunk * 68 + soff]) = (v2f){sn0, sn1};

                // halting partial: quad-uniform; sum rg over row (ror4+ror8),
                // then cross-row (bcast15+bcast31) -> lane63 = wave total
                float part = __builtin_fmaf(whv2.x, sn0, whv2.y * sn1);
                part = dpp_addf<0x124>(part);   // row_ror:4
                part = dpp_addf<0x128>(part);   // row_ror:8
                part = dpp_addf<0x142>(part);   // row_bcast15
                part = dpp_addf<0x143>(part);   // row_bcast31
                if (l == 63) plds[pp][w] = part;
                __syncthreads();

                float4 pa = *(const float4*)(&plds[pp][0]);
                float4 pb = *(const float4*)(&plds[pp][4]);
                float dot = ((pa.x + pa.y) + (pa.z + pa.w)) +
                            ((pb.x + pb.y) + (pb.z + pb.w));
                pp ^= 1;
                float p = __builtin_amdgcn_rcpf(
                    1.0f + __builtin_amdgcn_exp2f(-(dot + bhf) * L2E));
                bool halt = (cum + p > thresh) || (n == 3);
                float hw = 1.0f - cum;
                float wn = halt ? hw : p;
                accs = accs + wn * (v2f){sn0, sn1};
                nup += 1.0f;
                cum += wn;
                if (halt) { remt = hw; break; }   // exact: w==0 afterwards
                cur = nxt;
            }

            pc = (pc + nup + remt) * (1.0f / (float)T_);

            int hb = cur ^ 1;   // dead buffer -> becomes h
            av[k]  = accs;
            cu4[k] = cum;
            if (c == 0)
                *(v2f*)(&sbuf[hb][schunk * 68 + soff]) = accs;
            cur = hb;
            __syncthreads();
        }

        // batched stores: acc_s in place over dead U rows, + cum
        if (c == 0) {
            #pragma unroll
            for (int k = 0; k < 4; ++k)
                *(v2f*)(UAcc + (size_t)(tg * 4 + k) * H_ + rowbase) = av[k];
        }
        if (tid == 0) {
            #pragma unroll
            for (int k = 0; k < 4; ++k) cumArr[tg * 4 + k] = cu4[k];
        }
    }
    if (tid == 0) pc_out[0] = pc;
}

// ---------------- k_out: ys[t] = Wo@acc_s[t] + cum[t]*bo ----------------
__global__ void k_out(const float* __restrict__ AccS,
                      const float* __restrict__ Wo,
                      const float* __restrict__ bo,
                      const float* __restrict__ cumArr,
                      float* __restrict__ ys) {
    int t0 = blockIdx.x * 8;
    int tid = threadIdx.x;   // 256
    __shared__ float wo[IO_ * 257];
    __shared__ float as[8 * 260];
    for (int i = tid; i < IO_ * H_; i += 256) {
        int o = i / H_, h = i % H_;
        wo[o * 257 + h] = Wo[i];
    }
    for (int i = tid; i < 8 * H_; i += 256) {
        int tt = i / H_, h = i % H_;
        as[tt * 260 + h] = AccS[(size_t)t0 * H_ + i];
    }
    __syncthreads();
    int tt = tid >> 5, o = tid & 31;
    float acc = cumArr[t0 + tt] * bo[o];
    #pragma unroll 4
    for (int h = 0; h < H_; ++h) acc += wo[o * 257 + h] * as[tt * 260 + h];
    ys[(size_t)(t0 + tt) * IO_ + o] = acc;
}

extern "C" void kernel_launch(void* const* d_in, const int* in_sizes, int n_in,
                              void* d_out, int out_size, void* d_ws, size_t ws_size,
                              hipStream_t stream) {
    const float* x  = (const float*)d_in[0];
    const float* h0 = (const float*)d_in[1];
    const float* Wp = (const float*)d_in[2];
    const float* bp = (const float*)d_in[3];
    const float* Wx = (const float*)d_in[4];
    const float* Ws = (const float*)d_in[5];
    const float* b  = (const float*)d_in[6];
    const float* wh = (const float*)d_in[7];
    const float* bh = (const float*)d_in[8];
    const float* Wo = (const float*)d_in[9];
    const float* bo = (const float*)d_in[10];
    float* out = (float*)d_out;   // f32: ys[8192*32] then pc

    char* ws = (char*)d_ws;
    float* WxpT = (float*)ws;                                    //  32 KB
    float* cvec = (float*)(ws + 32768);                          //   1 KB
    float* cumA = (float*)(ws + 33792);                          //  32 KB
    float* UAcc = (float*)(ws + 66560);                          //   8 MB f32
    // total ws use: 8.45 MB (AccS aliases UAcc in place)

    k_prep<<<H_, 64, 0, stream>>>(Wx, Wp, bp, b, WxpT, cvec);
    k_u<<<T_ / 8, 256, 0, stream>>>(x, WxpT, cvec, UAcc);
    act_chain<<<1, 512, 0, stream>>>(Ws, Wx, wh, bh, h0, UAcc, cumA,
                                     out + (size_t)T_ * IO_);
    k_out<<<T_ / 8, 256, 0, stream>>>(UAcc, Wo, bo, cumA, out);
}